// Round 1
// baseline (1973.149 us; speedup 1.0000x reference)
//
#include <hip/hip_runtime.h>
#include <hip/hip_bf16.h>

#define TPB 256

// ---------------------------------------------------------------------------
// Fused Q/K/V projection: out = (h @ W^T + b) * scale, one blockIdx.y per matrix.
// Tile: 64 nodes x 128 outputs per block, 256 threads, K chunked by 32.
// Thread (colg = tid&31, nodeg = tid>>5) owns 8 nodes x 4 cols (cols colg+32*jj).
// ---------------------------------------------------------------------------
__global__ __launch_bounds__(256) void proj_kernel(
    const float* __restrict__ h,
    const float* __restrict__ Wq, const float* __restrict__ bq,
    const float* __restrict__ Wk, const float* __restrict__ bk,
    const float* __restrict__ Wv, const float* __restrict__ bv,
    float* __restrict__ qo, float* __restrict__ ko, float* __restrict__ vo,
    int n)
{
    const float* W; const float* bias; float* out; float scale;
    if (blockIdx.y == 0)      { W = Wq; bias = bq; out = qo; scale = 0.25f; } // D^-0.5
    else if (blockIdx.y == 1) { W = Wk; bias = bk; out = ko; scale = 1.0f; }
    else                      { W = Wv; bias = bv; out = vo; scale = 1.0f; }

    __shared__ float sh[64][128];   // h tile
    __shared__ float wl[128][33];   // W chunk [j][c], pad 33 -> conflict-free

    const int tid = threadIdx.x;
    const int nb  = blockIdx.x * 64;

    // load h tile (float4, coalesced)
    for (int idx = tid; idx < 64 * 32; idx += TPB) {
        int m = idx >> 5, c4 = idx & 31;
        float4 val = make_float4(0.f, 0.f, 0.f, 0.f);
        if (nb + m < n) val = *(const float4*)(h + (size_t)(nb + m) * 128 + c4 * 4);
        *(float4*)(&sh[m][c4 * 4]) = val;
    }

    const int colg  = tid & 31;
    const int nodeg = tid >> 5;
    float acc[8][4];
    #pragma unroll
    for (int mm = 0; mm < 8; ++mm)
        #pragma unroll
        for (int jj = 0; jj < 4; ++jj) acc[mm][jj] = 0.f;

    for (int cb = 0; cb < 128; cb += 32) {
        __syncthreads();
        // stage W chunk: rows j (all 128 outputs), cols cb..cb+31
        for (int idx = tid; idx < 128 * 32; idx += TPB) {
            int j = idx >> 5, c = idx & 31;
            wl[j][c] = W[(size_t)j * 128 + cb + c];
        }
        __syncthreads();
        #pragma unroll
        for (int c = 0; c < 32; ++c) {
            // banks: (33*colg + c) % 32 = (colg + c) % 32 -> conflict-free
            float w0 = wl[colg][c];
            float w1 = wl[colg + 32][c];
            float w2 = wl[colg + 64][c];
            float w3 = wl[colg + 96][c];
            #pragma unroll
            for (int mm = 0; mm < 8; ++mm) {
                float hv = sh[nodeg * 8 + mm][cb + c];  // 2-addr broadcast: free
                acc[mm][0] = fmaf(hv, w0, acc[mm][0]);
                acc[mm][1] = fmaf(hv, w1, acc[mm][1]);
                acc[mm][2] = fmaf(hv, w2, acc[mm][2]);
                acc[mm][3] = fmaf(hv, w3, acc[mm][3]);
            }
        }
    }

    float b0 = bias[colg], b1 = bias[colg + 32], b2 = bias[colg + 64], b3 = bias[colg + 96];
    #pragma unroll
    for (int mm = 0; mm < 8; ++mm) {
        int m = nb + nodeg * 8 + mm;
        if (m < n) {
            float* o = out + (size_t)m * 128;
            o[colg]      = (acc[mm][0] + b0) * scale;
            o[colg + 32] = (acc[mm][1] + b1) * scale;
            o[colg + 64] = (acc[mm][2] + b2) * scale;
            o[colg + 96] = (acc[mm][3] + b3) * scale;
        }
    }
}

// ---------------------------------------------------------------------------
// Edge pass A: logits -> exp -> store ex, atomic segment-sum of denominators.
// One thread per (edge, head). Layout: q[node*128 + d*8 + head] (head fast axis).
// Max-subtraction skipped: logits are O(1) here and softmax is shift-invariant.
// ---------------------------------------------------------------------------
__global__ __launch_bounds__(256) void edge_logits_kernel(
    const float* __restrict__ q, const float* __restrict__ k,
    const int* __restrict__ row, const int* __restrict__ col,
    float* __restrict__ ex, float* __restrict__ s, int E)
{
    long gid = (long)blockIdx.x * TPB + threadIdx.x;
    if (gid >= (long)E * 8) return;
    int e = (int)(gid >> 3), head = (int)(gid & 7);
    int r = row[e], c = col[e];
    const float* qp = q + (size_t)r * 128 + head;
    const float* kp = k + (size_t)c * 128 + head;
    float dot = 0.f;
    #pragma unroll
    for (int d = 0; d < 16; ++d) dot = fmaf(qp[d * 8], kp[d * 8], dot);
    float exv = __expf(dot);
    ex[gid] = exv;
    atomicAdd(&s[(size_t)r * 8 + head], exv);
}

// ---------------------------------------------------------------------------
// Edge pass B: attn = ex / s[row]; scatter-accumulate attn * v[col] into acc.
// ---------------------------------------------------------------------------
__global__ __launch_bounds__(256) void edge_spmm_kernel(
    const float* __restrict__ v,
    const int* __restrict__ row, const int* __restrict__ col,
    const float* __restrict__ ex, const float* __restrict__ s,
    float* __restrict__ acc, int E)
{
    long gid = (long)blockIdx.x * TPB + threadIdx.x;
    if (gid >= (long)E * 8) return;
    int e = (int)(gid >> 3), head = (int)(gid & 7);
    int r = row[e], c = col[e];
    float a = ex[gid] / s[(size_t)r * 8 + head];  // s > 0: contains at least this edge's exp
    const float* vp = v + (size_t)c * 128 + head;
    float* ap = acc + (size_t)r * 128 + head;
    #pragma unroll
    for (int d = 0; d < 16; ++d) atomicAdd(&ap[d * 8], a * vp[d * 8]);
}

// ---------------------------------------------------------------------------
// Output projection, in place on d_out: out = acc @ Wo^T + bo.
// Safe in-place: each block stages its own 64 rows in LDS before overwriting.
// ---------------------------------------------------------------------------
__global__ __launch_bounds__(256) void outproj_kernel(
    float* __restrict__ io, const float* __restrict__ Wo, const float* __restrict__ bo,
    int n)
{
    __shared__ float sh[64][128];
    __shared__ float wl[128][33];

    const int tid = threadIdx.x;
    const int nb  = blockIdx.x * 64;

    for (int idx = tid; idx < 64 * 32; idx += TPB) {
        int m = idx >> 5, c4 = idx & 31;
        float4 val = make_float4(0.f, 0.f, 0.f, 0.f);
        if (nb + m < n) val = *(const float4*)(io + (size_t)(nb + m) * 128 + c4 * 4);
        *(float4*)(&sh[m][c4 * 4]) = val;
    }

    const int colg  = tid & 31;
    const int nodeg = tid >> 5;
    float acc[8][4];
    #pragma unroll
    for (int mm = 0; mm < 8; ++mm)
        #pragma unroll
        for (int jj = 0; jj < 4; ++jj) acc[mm][jj] = 0.f;

    for (int cb = 0; cb < 128; cb += 32) {
        __syncthreads();
        for (int idx = tid; idx < 128 * 32; idx += TPB) {
            int j = idx >> 5, c = idx & 31;
            wl[j][c] = Wo[(size_t)j * 128 + cb + c];
        }
        __syncthreads();
        #pragma unroll
        for (int c = 0; c < 32; ++c) {
            float w0 = wl[colg][c];
            float w1 = wl[colg + 32][c];
            float w2 = wl[colg + 64][c];
            float w3 = wl[colg + 96][c];
            #pragma unroll
            for (int mm = 0; mm < 8; ++mm) {
                float hv = sh[nodeg * 8 + mm][cb + c];
                acc[mm][0] = fmaf(hv, w0, acc[mm][0]);
                acc[mm][1] = fmaf(hv, w1, acc[mm][1]);
                acc[mm][2] = fmaf(hv, w2, acc[mm][2]);
                acc[mm][3] = fmaf(hv, w3, acc[mm][3]);
            }
        }
    }

    float b0 = bo[colg], b1 = bo[colg + 32], b2 = bo[colg + 64], b3 = bo[colg + 96];
    #pragma unroll
    for (int mm = 0; mm < 8; ++mm) {
        int m = nb + nodeg * 8 + mm;
        if (m < n) {
            float* o = io + (size_t)m * 128;
            o[colg]      = acc[mm][0] + b0;
            o[colg + 32] = acc[mm][1] + b1;
            o[colg + 64] = acc[mm][2] + b2;
            o[colg + 96] = acc[mm][3] + b3;
        }
    }
}

// ---------------------------------------------------------------------------

extern "C" void kernel_launch(void* const* d_in, const int* in_sizes, int n_in,
                              void* d_out, int out_size, void* d_ws, size_t ws_size,
                              hipStream_t stream)
{
    const float* h  = (const float*)d_in[0];
    const int*   row = (const int*)d_in[1];
    const int*   col = (const int*)d_in[2];
    const float* Wq = (const float*)d_in[3];
    const float* bq = (const float*)d_in[4];
    const float* Wk = (const float*)d_in[5];
    const float* bk = (const float*)d_in[6];
    const float* Wv = (const float*)d_in[7];
    const float* bv = (const float*)d_in[8];
    const float* Wo = (const float*)d_in[9];
    const float* bo = (const float*)d_in[10];

    const int n = in_sizes[0] / 128;
    const int E = in_sizes[1];
    float* out = (float*)d_out;

    // workspace layout (all fp32)
    char* ws = (char*)d_ws;
    float* q  = (float*)ws; ws += (size_t)n * 128 * sizeof(float);
    float* k  = (float*)ws; ws += (size_t)n * 128 * sizeof(float);
    float* v  = (float*)ws; ws += (size_t)n * 128 * sizeof(float);
    float* ex = (float*)ws; ws += (size_t)E * 8 * sizeof(float);
    float* s  = (float*)ws; ws += (size_t)n * 8 * sizeof(float);
    size_t needed = (size_t)(ws - (char*)d_ws);
    if (ws_size < needed) return;  // workspace too small: bail (will fail validation loudly)

    // zero the atomic accumulators (ws/d_out are poisoned 0xAA before every launch)
    hipMemsetAsync(s, 0, (size_t)n * 8 * sizeof(float), stream);
    hipMemsetAsync(d_out, 0, (size_t)n * 128 * sizeof(float), stream);

    dim3 pgrid((n + 63) / 64, 3);
    proj_kernel<<<pgrid, TPB, 0, stream>>>(h, Wq, bq, Wk, bk, Wv, bv, q, k, v, n);

    long nthreads = (long)E * 8;
    int eblocks = (int)((nthreads + TPB - 1) / TPB);
    edge_logits_kernel<<<eblocks, TPB, 0, stream>>>(q, k, row, col, ex, s, E);
    edge_spmm_kernel<<<eblocks, TPB, 0, stream>>>(v, row, col, ex, s, out, E);

    outproj_kernel<<<(n + 63) / 64, TPB, 0, stream>>>(out, Wo, bo, n);
}

// Round 2
// 836.851 us; speedup vs baseline: 2.3578x; 2.3578x over previous
//
#include <hip/hip_runtime.h>
#include <hip/hip_bf16.h>

#define TPB 256
#define SCAN_T 256
#define SCAN_E 2048   // elements scanned per block (8 per thread)

// permuted layout: p = h*16 + d  <->  original o = d*8 + h
__device__ __forceinline__ int origcol(int p) { return ((p & 15) << 3) + (p >> 4); }

// ---------------------------------------------------------------------------
// Fused Q/K/V projection: out = (h @ W^T + b) * scale, written in HEAD-MAJOR
// layout out[m*128 + h*16 + d]. Permutation done by staging W rows permuted;
// all global loads/stores stay coalesced, LDS pattern unchanged.
// ---------------------------------------------------------------------------
__global__ __launch_bounds__(256) void proj_kernel(
    const float* __restrict__ h,
    const float* __restrict__ Wq, const float* __restrict__ bq,
    const float* __restrict__ Wk, const float* __restrict__ bk,
    const float* __restrict__ Wv, const float* __restrict__ bv,
    float* __restrict__ qo, float* __restrict__ ko, float* __restrict__ vo,
    int n)
{
    const float* W; const float* bias; float* out; float scale;
    if (blockIdx.y == 0)      { W = Wq; bias = bq; out = qo; scale = 0.25f; } // D^-0.5
    else if (blockIdx.y == 1) { W = Wk; bias = bk; out = ko; scale = 1.0f; }
    else                      { W = Wv; bias = bv; out = vo; scale = 1.0f; }

    __shared__ float sh[64][128];   // h tile
    __shared__ float wl[128][33];   // W chunk, rows permuted: wl[p] = W[origcol(p)]

    const int tid = threadIdx.x;
    const int nb  = blockIdx.x * 64;

    for (int idx = tid; idx < 64 * 32; idx += TPB) {
        int m = idx >> 5, c4 = idx & 31;
        float4 val = make_float4(0.f, 0.f, 0.f, 0.f);
        if (nb + m < n) val = *(const float4*)(h + (size_t)(nb + m) * 128 + c4 * 4);
        *(float4*)(&sh[m][c4 * 4]) = val;
    }

    const int colg  = tid & 31;
    const int nodeg = tid >> 5;
    float acc[8][4];
    #pragma unroll
    for (int mm = 0; mm < 8; ++mm)
        #pragma unroll
        for (int jj = 0; jj < 4; ++jj) acc[mm][jj] = 0.f;

    for (int cb = 0; cb < 128; cb += 32) {
        __syncthreads();
        for (int idx = tid; idx < 128 * 32; idx += TPB) {
            int p = idx >> 5, c = idx & 31;
            wl[p][c] = W[(size_t)origcol(p) * 128 + cb + c];
        }
        __syncthreads();
        #pragma unroll
        for (int c = 0; c < 32; ++c) {
            float w0 = wl[colg][c];
            float w1 = wl[colg + 32][c];
            float w2 = wl[colg + 64][c];
            float w3 = wl[colg + 96][c];
            #pragma unroll
            for (int mm = 0; mm < 8; ++mm) {
                float hv = sh[nodeg * 8 + mm][cb + c];
                acc[mm][0] = fmaf(hv, w0, acc[mm][0]);
                acc[mm][1] = fmaf(hv, w1, acc[mm][1]);
                acc[mm][2] = fmaf(hv, w2, acc[mm][2]);
                acc[mm][3] = fmaf(hv, w3, acc[mm][3]);
            }
        }
    }

    float b0 = bias[origcol(colg)];
    float b1 = bias[origcol(colg + 32)];
    float b2 = bias[origcol(colg + 64)];
    float b3 = bias[origcol(colg + 96)];
    #pragma unroll
    for (int mm = 0; mm < 8; ++mm) {
        int m = nb + nodeg * 8 + mm;
        if (m < n) {
            float* o = out + (size_t)m * 128;
            o[colg]      = (acc[mm][0] + b0) * scale;
            o[colg + 32] = (acc[mm][1] + b1) * scale;
            o[colg + 64] = (acc[mm][2] + b2) * scale;
            o[colg + 96] = (acc[mm][3] + b3) * scale;
        }
    }
}

// ---------------------------------------------------------------------------
// CSR build: histogram -> 2-level exclusive scan -> scatter col values.
// ---------------------------------------------------------------------------
__global__ __launch_bounds__(256) void hist_kernel(
    const int* __restrict__ row, int* __restrict__ cnt, int E)
{
    int e = blockIdx.x * 256 + threadIdx.x;
    if (e < E) atomicAdd(&cnt[row[e]], 1);
}

__global__ __launch_bounds__(SCAN_T) void scan1_kernel(
    const int* __restrict__ cnt, int* __restrict__ excl, int* __restrict__ btot, int n)
{
    __shared__ int sd[SCAN_T];
    int t = threadIdx.x, b = blockIdx.x;
    int base = b * SCAN_E + t * 8;
    int vals[8]; int sum = 0;
    #pragma unroll
    for (int i = 0; i < 8; ++i) {
        int idx = base + i;
        vals[i] = (idx < n) ? cnt[idx] : 0;
        sum += vals[i];
    }
    sd[t] = sum;
    __syncthreads();
    for (int off = 1; off < SCAN_T; off <<= 1) {
        int x = (t >= off) ? sd[t - off] : 0;
        __syncthreads();
        sd[t] += x;
        __syncthreads();
    }
    int run = sd[t] - sum;   // exclusive prefix of this thread's chunk
    #pragma unroll
    for (int i = 0; i < 8; ++i) {
        int idx = base + i;
        if (idx < n) excl[idx] = run;
        run += vals[i];
    }
    if (t == SCAN_T - 1) btot[b] = sd[t];
}

__global__ __launch_bounds__(SCAN_T) void scan2_kernel(int* __restrict__ btot, int nb)
{
    __shared__ int sd[SCAN_T];
    int t = threadIdx.x;
    int orig = (t < nb) ? btot[t] : 0;
    sd[t] = orig;
    __syncthreads();
    for (int off = 1; off < SCAN_T; off <<= 1) {
        int x = (t >= off) ? sd[t - off] : 0;
        __syncthreads();
        sd[t] += x;
        __syncthreads();
    }
    if (t < nb) btot[t] = sd[t] - orig;  // exclusive block offsets
}

__global__ __launch_bounds__(SCAN_T) void scan3_kernel(
    int* __restrict__ roff, int* __restrict__ cur, const int* __restrict__ btot, int n)
{
    int add = btot[blockIdx.x];
    int base = blockIdx.x * SCAN_E + threadIdx.x;
    #pragma unroll
    for (int i = 0; i < 8; ++i) {
        int idx = base + i * SCAN_T;
        if (idx < n) { int val = roff[idx] + add; roff[idx] = val; cur[idx] = val; }
    }
}

__global__ __launch_bounds__(256) void scatter_kernel(
    const int* __restrict__ row, const int* __restrict__ col,
    int* __restrict__ cur, int* __restrict__ ecol, int E)
{
    int e = blockIdx.x * 256 + threadIdx.x;
    if (e < E) {
        int pos = atomicAdd(&cur[row[e]], 1);
        ecol[pos] = col[e];
    }
}

// ---------------------------------------------------------------------------
// Fused attention: one wave per destination node. lane = j*8 + h.
// 8 lanes per head split the node's edges; single pass accumulates
// numerator (exp * v) and denominator (exp) in registers, butterfly-reduce,
// divide once. ao may alias q (per-wave read-then-write of the same row;
// q/ao deliberately NOT __restrict__).
// ---------------------------------------------------------------------------
__global__ __launch_bounds__(256) void attn_kernel(
    const float* q, const float* __restrict__ k, const float* __restrict__ v,
    const int* __restrict__ roff, const int* __restrict__ cnt,
    const int* __restrict__ ecol, float* ao, int n)
{
    int wave = threadIdx.x >> 6;
    int lane = threadIdx.x & 63;
    int i = blockIdx.x * 4 + wave;
    if (i >= n) return;
    int h = lane & 7;
    int j = lane >> 3;

    const float4* qp = (const float4*)(q + (size_t)i * 128 + h * 16);
    float4 q0 = qp[0], q1 = qp[1], q2 = qp[2], q3 = qp[3];

    float s = 0.f;
    float acc[16];
    #pragma unroll
    for (int d = 0; d < 16; ++d) acc[d] = 0.f;

    int start = roff[i];
    int end   = start + cnt[i];
    for (int p = start + j; p < end; p += 8) {
        int c = ecol[p];
        const float4* kp = (const float4*)(k + (size_t)c * 128 + h * 16);
        float4 k0 = kp[0], k1 = kp[1], k2 = kp[2], k3 = kp[3];
        float dot = q0.x * k0.x;
        dot = fmaf(q0.y, k0.y, dot); dot = fmaf(q0.z, k0.z, dot); dot = fmaf(q0.w, k0.w, dot);
        dot = fmaf(q1.x, k1.x, dot); dot = fmaf(q1.y, k1.y, dot); dot = fmaf(q1.z, k1.z, dot); dot = fmaf(q1.w, k1.w, dot);
        dot = fmaf(q2.x, k2.x, dot); dot = fmaf(q2.y, k2.y, dot); dot = fmaf(q2.z, k2.z, dot); dot = fmaf(q2.w, k2.w, dot);
        dot = fmaf(q3.x, k3.x, dot); dot = fmaf(q3.y, k3.y, dot); dot = fmaf(q3.z, k3.z, dot); dot = fmaf(q3.w, k3.w, dot);
        float ev = __expf(dot);
        s += ev;
        const float4* vp = (const float4*)(v + (size_t)c * 128 + h * 16);
        float4 v0 = vp[0], v1 = vp[1], v2 = vp[2], v3 = vp[3];
        acc[0]  = fmaf(ev, v0.x, acc[0]);  acc[1]  = fmaf(ev, v0.y, acc[1]);
        acc[2]  = fmaf(ev, v0.z, acc[2]);  acc[3]  = fmaf(ev, v0.w, acc[3]);
        acc[4]  = fmaf(ev, v1.x, acc[4]);  acc[5]  = fmaf(ev, v1.y, acc[5]);
        acc[6]  = fmaf(ev, v1.z, acc[6]);  acc[7]  = fmaf(ev, v1.w, acc[7]);
        acc[8]  = fmaf(ev, v2.x, acc[8]);  acc[9]  = fmaf(ev, v2.y, acc[9]);
        acc[10] = fmaf(ev, v2.z, acc[10]); acc[11] = fmaf(ev, v2.w, acc[11]);
        acc[12] = fmaf(ev, v3.x, acc[12]); acc[13] = fmaf(ev, v3.y, acc[13]);
        acc[14] = fmaf(ev, v3.z, acc[14]); acc[15] = fmaf(ev, v3.w, acc[15]);
    }

    // reduce across the 8 lanes (j = 0..7) sharing this head
    #pragma unroll
    for (int m = 8; m <= 32; m <<= 1) {
        s += __shfl_xor(s, m);
        #pragma unroll
        for (int d = 0; d < 16; ++d) acc[d] += __shfl_xor(acc[d], m);
    }

    if (j == 0) {
        float inv = (s > 0.f) ? 1.f / s : 0.f;
        float4* op = (float4*)(ao + (size_t)i * 128 + h * 16);
        op[0] = make_float4(acc[0]  * inv, acc[1]  * inv, acc[2]  * inv, acc[3]  * inv);
        op[1] = make_float4(acc[4]  * inv, acc[5]  * inv, acc[6]  * inv, acc[7]  * inv);
        op[2] = make_float4(acc[8]  * inv, acc[9]  * inv, acc[10] * inv, acc[11] * inv);
        op[3] = make_float4(acc[12] * inv, acc[13] * inv, acc[14] * inv, acc[15] * inv);
    }
}

// ---------------------------------------------------------------------------
// Output projection: out = ao @ Wo^T + bo, where ao is head-major.
// Wo columns are permuted during LDS staging to match.
// ---------------------------------------------------------------------------
__global__ __launch_bounds__(256) void outproj_kernel(
    const float* __restrict__ ao, const float* __restrict__ Wo,
    const float* __restrict__ bo, float* __restrict__ out, int n)
{
    __shared__ float sh[64][128];
    __shared__ float wl[128][33];

    const int tid = threadIdx.x;
    const int nb  = blockIdx.x * 64;

    for (int idx = tid; idx < 64 * 32; idx += TPB) {
        int m = idx >> 5, c4 = idx & 31;
        float4 val = make_float4(0.f, 0.f, 0.f, 0.f);
        if (nb + m < n) val = *(const float4*)(ao + (size_t)(nb + m) * 128 + c4 * 4);
        *(float4*)(&sh[m][c4 * 4]) = val;
    }

    const int colg  = tid & 31;
    const int nodeg = tid >> 5;
    float acc[8][4];
    #pragma unroll
    for (int mm = 0; mm < 8; ++mm)
        #pragma unroll
        for (int jj = 0; jj < 4; ++jj) acc[mm][jj] = 0.f;

    for (int cb = 0; cb < 128; cb += 32) {
        __syncthreads();
        // stage Wo with permuted columns: wl[j][c] = Wo[j][origcol(cb+c)]
        for (int idx = tid; idx < 128 * 32; idx += TPB) {
            int jrow = idx >> 5, c = idx & 31;
            wl[jrow][c] = Wo[(size_t)jrow * 128 + origcol(cb + c)];
        }
        __syncthreads();
        #pragma unroll
        for (int c = 0; c < 32; ++c) {
            float w0 = wl[colg][c];
            float w1 = wl[colg + 32][c];
            float w2 = wl[colg + 64][c];
            float w3 = wl[colg + 96][c];
            #pragma unroll
            for (int mm = 0; mm < 8; ++mm) {
                float hv = sh[nodeg * 8 + mm][cb + c];
                acc[mm][0] = fmaf(hv, w0, acc[mm][0]);
                acc[mm][1] = fmaf(hv, w1, acc[mm][1]);
                acc[mm][2] = fmaf(hv, w2, acc[mm][2]);
                acc[mm][3] = fmaf(hv, w3, acc[mm][3]);
            }
        }
    }

    float b0 = bo[colg], b1 = bo[colg + 32], b2 = bo[colg + 64], b3 = bo[colg + 96];
    #pragma unroll
    for (int mm = 0; mm < 8; ++mm) {
        int m = nb + nodeg * 8 + mm;
        if (m < n) {
            float* o = out + (size_t)m * 128;
            o[colg]      = acc[mm][0] + b0;
            o[colg + 32] = acc[mm][1] + b1;
            o[colg + 64] = acc[mm][2] + b2;
            o[colg + 96] = acc[mm][3] + b3;
        }
    }
}

// ---------------------------------------------------------------------------

extern "C" void kernel_launch(void* const* d_in, const int* in_sizes, int n_in,
                              void* d_out, int out_size, void* d_ws, size_t ws_size,
                              hipStream_t stream)
{
    const float* h   = (const float*)d_in[0];
    const int*   row = (const int*)d_in[1];
    const int*   col = (const int*)d_in[2];
    const float* Wq  = (const float*)d_in[3];
    const float* bq  = (const float*)d_in[4];
    const float* Wk  = (const float*)d_in[5];
    const float* bk  = (const float*)d_in[6];
    const float* Wv  = (const float*)d_in[7];
    const float* bv  = (const float*)d_in[8];
    const float* Wo  = (const float*)d_in[9];
    const float* bo  = (const float*)d_in[10];

    const int n = in_sizes[0] / 128;
    const int E = in_sizes[1];
    float* out = (float*)d_out;

    // workspace layout
    char* ws = (char*)d_ws;
    float* q   = (float*)ws; ws += (size_t)n * 128 * sizeof(float);
    float* kk  = (float*)ws; ws += (size_t)n * 128 * sizeof(float);
    float* vv  = (float*)ws; ws += (size_t)n * 128 * sizeof(float);
    int* cnt   = (int*)ws;   ws += (size_t)n * sizeof(int);
    int* roff  = (int*)ws;   ws += (size_t)n * sizeof(int);
    int* cur   = (int*)ws;   ws += (size_t)n * sizeof(int);
    int* ecol  = (int*)ws;   ws += (size_t)E * sizeof(int);
    int* btot  = (int*)ws;   ws += 256 * sizeof(int);
    float* ao  = q;          // alias: attn reads q[i] (registers) before storing ao[i]
    if (ws_size < (size_t)(ws - (char*)d_ws)) return;

    hipMemsetAsync(cnt, 0, (size_t)n * sizeof(int), stream);

    dim3 pgrid((n + 63) / 64, 3);
    proj_kernel<<<pgrid, TPB, 0, stream>>>(h, Wq, bq, Wk, bk, Wv, bv, q, kk, vv, n);

    int eblocks = (E + 255) / 256;
    hist_kernel<<<eblocks, 256, 0, stream>>>(row, cnt, E);

    int nb = (n + SCAN_E - 1) / SCAN_E;   // 49 for n=100k (must be <= 256)
    scan1_kernel<<<nb, SCAN_T, 0, stream>>>(cnt, roff, btot, n);
    scan2_kernel<<<1, SCAN_T, 0, stream>>>(btot, nb);
    scan3_kernel<<<nb, SCAN_T, 0, stream>>>(roff, cur, btot, n);
    scatter_kernel<<<eblocks, 256, 0, stream>>>(row, col, cur, ecol, E);

    attn_kernel<<<(n + 3) / 4, TPB, 0, stream>>>(q, kk, vv, roff, cnt, ecol, ao, n);

    outproj_kernel<<<(n + 63) / 64, TPB, 0, stream>>>(ao, Wo, bo, out, n);
}

// Round 3
// 546.409 us; speedup vs baseline: 3.6111x; 1.5315x over previous
//
#include <hip/hip_runtime.h>
#include <hip/hip_bf16.h>

#define TPB 256
#define SCAN_T 256
#define SCAN_E 2048   // elements scanned per block (8 per thread)

typedef __attribute__((ext_vector_type(8))) short bf16x8;
typedef __attribute__((ext_vector_type(4))) float f32x4;

// permuted layout: p = h*16 + d  <->  original o = d*8 + h
__device__ __forceinline__ int origcol(int p) { return ((p & 15) << 3) + (p >> 4); }

// fp32 -> bf16 round-to-nearest-even (no header-internals dependency)
__device__ __forceinline__ unsigned short f2bf(float f) {
    unsigned int u = __float_as_uint(f);
    u += 0x7fffu + ((u >> 16) & 1u);
    return (unsigned short)(u >> 16);
}
__device__ __forceinline__ float bf2f_lo(unsigned int w) { return __uint_as_float(w << 16); }
__device__ __forceinline__ float bf2f_hi(unsigned int w) { return __uint_as_float(w & 0xffff0000u); }

// ---------------------------------------------------------------------------
// Fused Q/K/V projection via bf16 MFMA. Per block: 64 nodes x 128 outputs x 3
// matrices, 4 waves (each wave: 16 nodes). A-fragments (h rows) loaded directly
// from global fp32 -> bf16 regs; W staged to LDS bf16 per 32-wide K-chunk with
// head-major row permutation. Outputs bf16 head-major.
// K-permutation safety: A and B frags use the SAME k-enumeration (8 consecutive
// elements at kk*32 + g*8), so any hardware k-order gives the correct dot.
// C/D layout (measured): col = lane&15, row = (lane>>4)*4 + reg.
// ---------------------------------------------------------------------------
__global__ __launch_bounds__(256) void proj_kernel(
    const float* __restrict__ h,
    const float* __restrict__ Wq, const float* __restrict__ bq,
    const float* __restrict__ Wk, const float* __restrict__ bk,
    const float* __restrict__ Wv, const float* __restrict__ bv,
    unsigned short* __restrict__ qo, unsigned short* __restrict__ ko,
    unsigned short* __restrict__ vo, int n)
{
    __shared__ unsigned short wl[3][128][32];  // 24 KB, row p = head-major output col
    __shared__ float bias_lds[3][128];

    const int tid  = threadIdx.x;
    const int nb   = blockIdx.x * 64;
    const int wv   = tid >> 6;
    const int lane = tid & 63;
    const int jj   = lane & 15;
    const int g    = lane >> 4;

    // stage permuted biases (384 entries, 256 threads)
    for (int t = tid; t < 384; t += TPB) {
        int mat = t >> 7, p = t & 127;
        const float* bsrc = (mat == 0) ? bq : ((mat == 1) ? bk : bv);
        bias_lds[mat][p] = bsrc[origcol(p)];
    }

    // preload A fragments for all 4 K-chunks: row = nb + wv*16 + jj
    const int node_a = nb + wv * 16 + jj;
    bf16x8 afrag[4];
    #pragma unroll
    for (int kk = 0; kk < 4; ++kk) {
        float fv[8];
        if (node_a < n) {
            const float4* src = (const float4*)(h + (size_t)node_a * 128 + kk * 32 + g * 8);
            float4 x0 = src[0], x1 = src[1];
            fv[0] = x0.x; fv[1] = x0.y; fv[2] = x0.z; fv[3] = x0.w;
            fv[4] = x1.x; fv[5] = x1.y; fv[6] = x1.z; fv[7] = x1.w;
        } else {
            #pragma unroll
            for (int i = 0; i < 8; ++i) fv[i] = 0.f;
        }
        bf16x8 a;
        #pragma unroll
        for (int i = 0; i < 8; ++i) a[i] = (short)f2bf(fv[i]);
        afrag[kk] = a;
    }

    f32x4 acc[3][8];
    #pragma unroll
    for (int m = 0; m < 3; ++m)
        #pragma unroll
        for (int ct = 0; ct < 8; ++ct) { f32x4 z = {0.f, 0.f, 0.f, 0.f}; acc[m][ct] = z; }

    for (int kk = 0; kk < 4; ++kk) {
        __syncthreads();
        // stage W chunk: 3 mats x 128 rows (permuted) x 32 cols; 3072 float4s
        #pragma unroll
        for (int it = 0; it < 12; ++it) {
            int idx = tid + it * TPB;      // 0..3071
            int mat = idx >> 10;
            int rem = idx & 1023;
            int p   = rem >> 3;
            int f4  = rem & 7;
            const float* wsrc = (mat == 0) ? Wq : ((mat == 1) ? Wk : Wv);
            float4 x = *(const float4*)(wsrc + (size_t)origcol(p) * 128 + kk * 32 + f4 * 4);
            unsigned int w0 = (unsigned int)f2bf(x.x) | ((unsigned int)f2bf(x.y) << 16);
            unsigned int w1 = (unsigned int)f2bf(x.z) | ((unsigned int)f2bf(x.w) << 16);
            *(uint2*)(&wl[mat][p][f4 * 4]) = make_uint2(w0, w1);
        }
        __syncthreads();
        #pragma unroll
        for (int mat = 0; mat < 3; ++mat) {
            #pragma unroll
            for (int ct = 0; ct < 8; ++ct) {
                bf16x8 b = *(const bf16x8*)(&wl[mat][ct * 16 + jj][g * 8]);
                acc[mat][ct] = __builtin_amdgcn_mfma_f32_16x16x32_bf16(afrag[kk], b, acc[mat][ct], 0, 0, 0);
            }
        }
    }

    // epilogue: D row = (lane>>4)*4 + r (node), col = lane&15 within ct tile
    #pragma unroll
    for (int mat = 0; mat < 3; ++mat) {
        unsigned short* outp = (mat == 0) ? qo : ((mat == 1) ? ko : vo);
        const float scale = (mat == 0) ? 0.25f : 1.0f;   // D^-0.5 on q
        #pragma unroll
        for (int ct = 0; ct < 8; ++ct) {
            int p = ct * 16 + jj;
            float bsv = bias_lds[mat][p];
            #pragma unroll
            for (int r = 0; r < 4; ++r) {
                int node = nb + wv * 16 + g * 4 + r;
                if (node < n)
                    outp[(size_t)node * 128 + p] = f2bf((acc[mat][ct][r] + bsv) * scale);
            }
        }
    }
}

// ---------------------------------------------------------------------------
// CSR build: histogram -> 2-level exclusive scan -> scatter col values.
// ---------------------------------------------------------------------------
__global__ __launch_bounds__(256) void hist_kernel(
    const int* __restrict__ row, int* __restrict__ cnt, int E)
{
    int e = blockIdx.x * 256 + threadIdx.x;
    if (e < E) atomicAdd(&cnt[row[e]], 1);
}

__global__ __launch_bounds__(SCAN_T) void scan1_kernel(
    const int* __restrict__ cnt, int* __restrict__ excl, int* __restrict__ btot, int n)
{
    __shared__ int sd[SCAN_T];
    int t = threadIdx.x, b = blockIdx.x;
    int base = b * SCAN_E + t * 8;
    int vals[8]; int sum = 0;
    #pragma unroll
    for (int i = 0; i < 8; ++i) {
        int idx = base + i;
        vals[i] = (idx < n) ? cnt[idx] : 0;
        sum += vals[i];
    }
    sd[t] = sum;
    __syncthreads();
    for (int off = 1; off < SCAN_T; off <<= 1) {
        int x = (t >= off) ? sd[t - off] : 0;
        __syncthreads();
        sd[t] += x;
        __syncthreads();
    }
    int run = sd[t] - sum;
    #pragma unroll
    for (int i = 0; i < 8; ++i) {
        int idx = base + i;
        if (idx < n) excl[idx] = run;
        run += vals[i];
    }
    if (t == SCAN_T - 1) btot[b] = sd[t];
}

__global__ __launch_bounds__(SCAN_T) void scan2_kernel(int* __restrict__ btot, int nb)
{
    __shared__ int sd[SCAN_T];
    int t = threadIdx.x;
    int orig = (t < nb) ? btot[t] : 0;
    sd[t] = orig;
    __syncthreads();
    for (int off = 1; off < SCAN_T; off <<= 1) {
        int x = (t >= off) ? sd[t - off] : 0;
        __syncthreads();
        sd[t] += x;
        __syncthreads();
    }
    if (t < nb) btot[t] = sd[t] - orig;
}

__global__ __launch_bounds__(SCAN_T) void scan3_kernel(
    int* __restrict__ roff, int* __restrict__ cur, const int* __restrict__ btot, int n)
{
    int add = btot[blockIdx.x];
    int base = blockIdx.x * SCAN_E + threadIdx.x;
    #pragma unroll
    for (int i = 0; i < 8; ++i) {
        int idx = base + i * SCAN_T;
        if (idx < n) { int val = roff[idx] + add; roff[idx] = val; cur[idx] = val; }
    }
}

__global__ __launch_bounds__(256) void scatter_kernel(
    const int* __restrict__ row, const int* __restrict__ col,
    int* __restrict__ cur, int* __restrict__ ecol, int E)
{
    int e = blockIdx.x * 256 + threadIdx.x;
    if (e < E) {
        int pos = atomicAdd(&cur[row[e]], 1);
        ecol[pos] = col[e];
    }
}

// ---------------------------------------------------------------------------
// Fused attention, bf16 q/k/v (head-major). One wave per destination node,
// lane = j*8 + h: 8 lanes per head split the edge list. Single pass: running
// numerator/denominator in registers, butterfly reduce, one divide.
// ao aliases q (wave reads q[i] into regs before its own store of ao[i]).
// ---------------------------------------------------------------------------
__global__ __launch_bounds__(256) void attn_kernel(
    const unsigned short* q, const unsigned short* __restrict__ k,
    const unsigned short* __restrict__ v,
    const int* __restrict__ roff, const int* __restrict__ cnt,
    const int* __restrict__ ecol, unsigned short* ao, int n)
{
    int wave = threadIdx.x >> 6;
    int lane = threadIdx.x & 63;
    int i = blockIdx.x * 4 + wave;
    if (i >= n) return;
    int hh = lane & 7;
    int j  = lane >> 3;

    // q row, head hh: 16 bf16 = 32B
    float qf[16];
    {
        const uint4* qp = (const uint4*)(q + (size_t)i * 128 + hh * 16);
        uint4 a = qp[0], b = qp[1];
        qf[0] = bf2f_lo(a.x);  qf[1] = bf2f_hi(a.x);  qf[2]  = bf2f_lo(a.y);  qf[3]  = bf2f_hi(a.y);
        qf[4] = bf2f_lo(a.z);  qf[5] = bf2f_hi(a.z);  qf[6]  = bf2f_lo(a.w);  qf[7]  = bf2f_hi(a.w);
        qf[8] = bf2f_lo(b.x);  qf[9] = bf2f_hi(b.x);  qf[10] = bf2f_lo(b.y);  qf[11] = bf2f_hi(b.y);
        qf[12]= bf2f_lo(b.z);  qf[13]= bf2f_hi(b.z);  qf[14] = bf2f_lo(b.w);  qf[15] = bf2f_hi(b.w);
    }

    float s = 0.f;
    float acc[16];
    #pragma unroll
    for (int d = 0; d < 16; ++d) acc[d] = 0.f;

    int start = roff[i];
    int end   = start + cnt[i];
    for (int p = start + j; p < end; p += 8) {
        int c = ecol[p];
        const uint4* kp = (const uint4*)(k + (size_t)c * 128 + hh * 16);
        uint4 ka = kp[0], kb = kp[1];
        float dot;
        dot = qf[0] * bf2f_lo(ka.x);
        dot = fmaf(qf[1],  bf2f_hi(ka.x), dot); dot = fmaf(qf[2],  bf2f_lo(ka.y), dot);
        dot = fmaf(qf[3],  bf2f_hi(ka.y), dot); dot = fmaf(qf[4],  bf2f_lo(ka.z), dot);
        dot = fmaf(qf[5],  bf2f_hi(ka.z), dot); dot = fmaf(qf[6],  bf2f_lo(ka.w), dot);
        dot = fmaf(qf[7],  bf2f_hi(ka.w), dot); dot = fmaf(qf[8],  bf2f_lo(kb.x), dot);
        dot = fmaf(qf[9],  bf2f_hi(kb.x), dot); dot = fmaf(qf[10], bf2f_lo(kb.y), dot);
        dot = fmaf(qf[11], bf2f_hi(kb.y), dot); dot = fmaf(qf[12], bf2f_lo(kb.z), dot);
        dot = fmaf(qf[13], bf2f_hi(kb.z), dot); dot = fmaf(qf[14], bf2f_lo(kb.w), dot);
        dot = fmaf(qf[15], bf2f_hi(kb.w), dot);
        float ev = __expf(dot);
        s += ev;
        const uint4* vp = (const uint4*)(v + (size_t)c * 128 + hh * 16);
        uint4 va = vp[0], vb = vp[1];
        acc[0]  = fmaf(ev, bf2f_lo(va.x), acc[0]);  acc[1]  = fmaf(ev, bf2f_hi(va.x), acc[1]);
        acc[2]  = fmaf(ev, bf2f_lo(va.y), acc[2]);  acc[3]  = fmaf(ev, bf2f_hi(va.y), acc[3]);
        acc[4]  = fmaf(ev, bf2f_lo(va.z), acc[4]);  acc[5]  = fmaf(ev, bf2f_hi(va.z), acc[5]);
        acc[6]  = fmaf(ev, bf2f_lo(va.w), acc[6]);  acc[7]  = fmaf(ev, bf2f_hi(va.w), acc[7]);
        acc[8]  = fmaf(ev, bf2f_lo(vb.x), acc[8]);  acc[9]  = fmaf(ev, bf2f_hi(vb.x), acc[9]);
        acc[10] = fmaf(ev, bf2f_lo(vb.y), acc[10]); acc[11] = fmaf(ev, bf2f_hi(vb.y), acc[11]);
        acc[12] = fmaf(ev, bf2f_lo(vb.z), acc[12]); acc[13] = fmaf(ev, bf2f_hi(vb.z), acc[13]);
        acc[14] = fmaf(ev, bf2f_lo(vb.w), acc[14]); acc[15] = fmaf(ev, bf2f_hi(vb.w), acc[15]);
    }

    #pragma unroll
    for (int m = 8; m <= 32; m <<= 1) {
        s += __shfl_xor(s, m);
        #pragma unroll
        for (int d = 0; d < 16; ++d) acc[d] += __shfl_xor(acc[d], m);
    }

    if (j == 0) {
        float inv = (s > 0.f) ? 1.f / s : 0.f;
        unsigned int w[8];
        #pragma unroll
        for (int d = 0; d < 8; ++d)
            w[d] = (unsigned int)f2bf(acc[2 * d] * inv) |
                   ((unsigned int)f2bf(acc[2 * d + 1] * inv) << 16);
        uint4* op = (uint4*)(ao + (size_t)i * 128 + hh * 16);
        op[0] = make_uint4(w[0], w[1], w[2], w[3]);
        op[1] = make_uint4(w[4], w[5], w[6], w[7]);
    }
}

// ---------------------------------------------------------------------------
// Output projection via bf16 MFMA: out = ao @ Wo^T + bo (fp32 out).
// ao is head-major, so Wo's K-dim (columns) is permuted during staging.
// ---------------------------------------------------------------------------
__global__ __launch_bounds__(256) void outproj_kernel(
    const unsigned short* __restrict__ ao, const float* __restrict__ Wo,
    const float* __restrict__ bo, float* __restrict__ out, int n)
{
    __shared__ unsigned short wl[128][32];  // 8 KB
    __shared__ float bias_lds[128];

    const int tid  = threadIdx.x;
    const int nb   = blockIdx.x * 64;
    const int wv   = tid >> 6;
    const int lane = tid & 63;
    const int jj   = lane & 15;
    const int g    = lane >> 4;

    if (tid < 128) bias_lds[tid] = bo[tid];

    const int node_a = nb + wv * 16 + jj;
    bf16x8 afrag[4];
    #pragma unroll
    for (int kk = 0; kk < 4; ++kk) {
        if (node_a < n)
            afrag[kk] = *(const bf16x8*)(ao + (size_t)node_a * 128 + kk * 32 + g * 8);
        else {
            bf16x8 z;
            #pragma unroll
            for (int i = 0; i < 8; ++i) z[i] = 0;
            afrag[kk] = z;
        }
    }

    f32x4 acc[8];
    #pragma unroll
    for (int ct = 0; ct < 8; ++ct) { f32x4 z = {0.f, 0.f, 0.f, 0.f}; acc[ct] = z; }

    for (int kk = 0; kk < 4; ++kk) {
        __syncthreads();
        // stage Wo chunk with permuted K: wl[j][c] = Wo[j][origcol(kk*32+c)]
        #pragma unroll
        for (int it = 0; it < 16; ++it) {
            int idx = tid + it * TPB;   // 0..4095
            int j = idx >> 5, c = idx & 31;
            wl[j][c] = f2bf(Wo[(size_t)j * 128 + origcol(kk * 32 + c)]);
        }
        __syncthreads();
        #pragma unroll
        for (int ct = 0; ct < 8; ++ct) {
            bf16x8 b = *(const bf16x8*)(&wl[ct * 16 + jj][g * 8]);
            acc[ct] = __builtin_amdgcn_mfma_f32_16x16x32_bf16(afrag[kk], b, acc[ct], 0, 0, 0);
        }
    }

    #pragma unroll
    for (int ct = 0; ct < 8; ++ct) {
        int j = ct * 16 + jj;
        float bsv = bias_lds[j];
        #pragma unroll
        for (int r = 0; r < 4; ++r) {
            int node = nb + wv * 16 + g * 4 + r;
            if (node < n)
                out[(size_t)node * 128 + j] = acc[ct][r] + bsv;
        }
    }
}

// ---------------------------------------------------------------------------

extern "C" void kernel_launch(void* const* d_in, const int* in_sizes, int n_in,
                              void* d_out, int out_size, void* d_ws, size_t ws_size,
                              hipStream_t stream)
{
    const float* h   = (const float*)d_in[0];
    const int*   row = (const int*)d_in[1];
    const int*   col = (const int*)d_in[2];
    const float* Wq  = (const float*)d_in[3];
    const float* bq  = (const float*)d_in[4];
    const float* Wk  = (const float*)d_in[5];
    const float* bk  = (const float*)d_in[6];
    const float* Wv  = (const float*)d_in[7];
    const float* bv  = (const float*)d_in[8];
    const float* Wo  = (const float*)d_in[9];
    const float* bo  = (const float*)d_in[10];

    const int n = in_sizes[0] / 128;
    const int E = in_sizes[1];
    float* out = (float*)d_out;

    // workspace layout
    char* ws = (char*)d_ws;
    unsigned short* q  = (unsigned short*)ws; ws += (size_t)n * 128 * sizeof(unsigned short);
    unsigned short* kk = (unsigned short*)ws; ws += (size_t)n * 128 * sizeof(unsigned short);
    unsigned short* vv = (unsigned short*)ws; ws += (size_t)n * 128 * sizeof(unsigned short);
    int* cnt  = (int*)ws; ws += (size_t)n * sizeof(int);
    int* roff = (int*)ws; ws += (size_t)n * sizeof(int);
    int* cur  = (int*)ws; ws += (size_t)n * sizeof(int);
    int* ecol = (int*)ws; ws += (size_t)E * sizeof(int);
    int* btot = (int*)ws; ws += 256 * sizeof(int);
    unsigned short* ao = q;   // alias: attn reads q[i] into regs before storing ao[i]
    if (ws_size < (size_t)(ws - (char*)d_ws)) return;

    hipMemsetAsync(cnt, 0, (size_t)n * sizeof(int), stream);

    proj_kernel<<<(n + 63) / 64, TPB, 0, stream>>>(h, Wq, bq, Wk, bk, Wv, bv, q, kk, vv, n);

    int eblocks = (E + 255) / 256;
    hist_kernel<<<eblocks, 256, 0, stream>>>(row, cnt, E);

    int nsb = (n + SCAN_E - 1) / SCAN_E;   // 49 for n=100k (<= 256)
    scan1_kernel<<<nsb, SCAN_T, 0, stream>>>(cnt, roff, btot, n);
    scan2_kernel<<<1, SCAN_T, 0, stream>>>(btot, nsb);
    scan3_kernel<<<nsb, SCAN_T, 0, stream>>>(roff, cur, btot, n);
    scatter_kernel<<<eblocks, 256, 0, stream>>>(row, col, cur, ecol, E);

    attn_kernel<<<(n + 3) / 4, TPB, 0, stream>>>(q, kk, vv, roff, cnt, ecol, ao, n);

    outproj_kernel<<<(n + 63) / 64, TPB, 0, stream>>>(ao, Wo, bo, out, n);
}

// Round 4
// 532.092 us; speedup vs baseline: 3.7083x; 1.0269x over previous
//
#include <hip/hip_runtime.h>
#include <hip/hip_bf16.h>

#define TPB 256
#define SCAN_T 256
#define SCAN_E 2048   // elements scanned per block (8 per thread)
#define EDGE_B 8      // edges per thread in hist/scatter (ILP)

typedef __attribute__((ext_vector_type(8))) short bf16x8;
typedef __attribute__((ext_vector_type(4))) float f32x4;

// permuted layout: p = h*16 + d  <->  original o = d*8 + h
__device__ __forceinline__ int origcol(int p) { return ((p & 15) << 3) + (p >> 4); }

// fp32 -> bf16 round-to-nearest-even
__device__ __forceinline__ unsigned short f2bf(float f) {
    unsigned int u = __float_as_uint(f);
    u += 0x7fffu + ((u >> 16) & 1u);
    return (unsigned short)(u >> 16);
}
__device__ __forceinline__ float bf2f_lo(unsigned int w) { return __uint_as_float(w << 16); }
__device__ __forceinline__ float bf2f_hi(unsigned int w) { return __uint_as_float(w & 0xffff0000u); }

// ---------------------------------------------------------------------------
// Fused {Q/K/V projection via bf16 MFMA} + {edge histogram}.
// Blocks [0, projBlocks): projection, 64 nodes x (3 x 128 outputs) each.
//   q written head-major to qo[node*128 + h*16 + d];
//   k,v interleaved: kv[node*256 + h*32 + d] (k) / + 16 (v)  -- one 64B line
//   per (node, head) holding both k and v fragments for the gather hot loop.
// Blocks [projBlocks, ...): histogram of `row` with 8 edges/thread ILP.
// ---------------------------------------------------------------------------
__global__ __launch_bounds__(256) void proj_hist_kernel(
    const float* __restrict__ h,
    const float* __restrict__ Wq, const float* __restrict__ bq,
    const float* __restrict__ Wk, const float* __restrict__ bk,
    const float* __restrict__ Wv, const float* __restrict__ bv,
    unsigned short* __restrict__ qo, unsigned short* __restrict__ kv,
    int n,
    const int* __restrict__ row, int* __restrict__ cnt, int E, int projBlocks)
{
    if ((int)blockIdx.x >= projBlocks) {
        // ---- histogram part: 8 edges per thread, independent atomics ----
        int t = (blockIdx.x - projBlocks) * TPB + threadIdx.x;
        int base = t * EDGE_B;
        if (base >= E) return;
        if (base + EDGE_B <= E) {
            int4 r0 = *(const int4*)(row + base);
            int4 r1 = *(const int4*)(row + base + 4);
            atomicAdd(&cnt[r0.x], 1); atomicAdd(&cnt[r0.y], 1);
            atomicAdd(&cnt[r0.z], 1); atomicAdd(&cnt[r0.w], 1);
            atomicAdd(&cnt[r1.x], 1); atomicAdd(&cnt[r1.y], 1);
            atomicAdd(&cnt[r1.z], 1); atomicAdd(&cnt[r1.w], 1);
        } else {
            for (int i = base; i < E; ++i) atomicAdd(&cnt[row[i]], 1);
        }
        return;
    }

    __shared__ unsigned short wl[3][128][32];  // 24 KB
    __shared__ float bias_lds[3][128];

    const int tid  = threadIdx.x;
    const int nb   = blockIdx.x * 64;
    const int wv   = tid >> 6;
    const int lane = tid & 63;
    const int jj   = lane & 15;
    const int g    = lane >> 4;

    for (int t = tid; t < 384; t += TPB) {
        int mat = t >> 7, p = t & 127;
        const float* bsrc = (mat == 0) ? bq : ((mat == 1) ? bk : bv);
        bias_lds[mat][p] = bsrc[origcol(p)];
    }

    // A fragments: row = nb + wv*16 + jj, 8 consecutive k-elems at kk*32+g*8
    const int node_a = nb + wv * 16 + jj;
    bf16x8 afrag[4];
    #pragma unroll
    for (int kk = 0; kk < 4; ++kk) {
        float fv[8];
        if (node_a < n) {
            const float4* src = (const float4*)(h + (size_t)node_a * 128 + kk * 32 + g * 8);
            float4 x0 = src[0], x1 = src[1];
            fv[0] = x0.x; fv[1] = x0.y; fv[2] = x0.z; fv[3] = x0.w;
            fv[4] = x1.x; fv[5] = x1.y; fv[6] = x1.z; fv[7] = x1.w;
        } else {
            #pragma unroll
            for (int i = 0; i < 8; ++i) fv[i] = 0.f;
        }
        bf16x8 a;
        #pragma unroll
        for (int i = 0; i < 8; ++i) a[i] = (short)f2bf(fv[i]);
        afrag[kk] = a;
    }

    f32x4 acc[3][8];
    #pragma unroll
    for (int m = 0; m < 3; ++m)
        #pragma unroll
        for (int ct = 0; ct < 8; ++ct) { f32x4 z = {0.f, 0.f, 0.f, 0.f}; acc[m][ct] = z; }

    for (int kk = 0; kk < 4; ++kk) {
        __syncthreads();
        #pragma unroll
        for (int it = 0; it < 12; ++it) {
            int idx = tid + it * TPB;      // 0..3071
            int mat = idx >> 10;
            int rem = idx & 1023;
            int p   = rem >> 3;
            int f4  = rem & 7;
            const float* wsrc = (mat == 0) ? Wq : ((mat == 1) ? Wk : Wv);
            float4 x = *(const float4*)(wsrc + (size_t)origcol(p) * 128 + kk * 32 + f4 * 4);
            unsigned int w0 = (unsigned int)f2bf(x.x) | ((unsigned int)f2bf(x.y) << 16);
            unsigned int w1 = (unsigned int)f2bf(x.z) | ((unsigned int)f2bf(x.w) << 16);
            *(uint2*)(&wl[mat][p][f4 * 4]) = make_uint2(w0, w1);
        }
        __syncthreads();
        #pragma unroll
        for (int mat = 0; mat < 3; ++mat) {
            #pragma unroll
            for (int ct = 0; ct < 8; ++ct) {
                bf16x8 b = *(const bf16x8*)(&wl[mat][ct * 16 + jj][g * 8]);
                acc[mat][ct] = __builtin_amdgcn_mfma_f32_16x16x32_bf16(afrag[kk], b, acc[mat][ct], 0, 0, 0);
            }
        }
    }

    // epilogue: D row (node) = (lane>>4)*4 + r, col = ct*16 + jj
    #pragma unroll
    for (int mat = 0; mat < 3; ++mat) {
        const float scale = (mat == 0) ? 0.25f : 1.0f;   // D^-0.5 on q
        #pragma unroll
        for (int ct = 0; ct < 8; ++ct) {
            int p = ct * 16 + jj;
            float bsv = bias_lds[mat][p];
            #pragma unroll
            for (int r = 0; r < 4; ++r) {
                int node = nb + wv * 16 + g * 4 + r;
                if (node < n) {
                    unsigned short val = f2bf((acc[mat][ct][r] + bsv) * scale);
                    if (mat == 0)
                        qo[(size_t)node * 128 + p] = val;
                    else {
                        // kv interleaved: head = p>>4, d = p&15; +16 for v
                        size_t addr = (size_t)node * 256 + ((p >> 4) << 5) + (p & 15)
                                      + ((mat == 2) ? 16 : 0);
                        kv[addr] = val;
                    }
                }
            }
        }
    }
}

// ---------------------------------------------------------------------------
// CSR scans
// ---------------------------------------------------------------------------
__global__ __launch_bounds__(SCAN_T) void scan1_kernel(
    const int* __restrict__ cnt, int* __restrict__ excl, int* __restrict__ btot, int n)
{
    __shared__ int sd[SCAN_T];
    int t = threadIdx.x, b = blockIdx.x;
    int base = b * SCAN_E + t * 8;
    int vals[8]; int sum = 0;
    #pragma unroll
    for (int i = 0; i < 8; ++i) {
        int idx = base + i;
        vals[i] = (idx < n) ? cnt[idx] : 0;
        sum += vals[i];
    }
    sd[t] = sum;
    __syncthreads();
    for (int off = 1; off < SCAN_T; off <<= 1) {
        int x = (t >= off) ? sd[t - off] : 0;
        __syncthreads();
        sd[t] += x;
        __syncthreads();
    }
    int run = sd[t] - sum;
    #pragma unroll
    for (int i = 0; i < 8; ++i) {
        int idx = base + i;
        if (idx < n) excl[idx] = run;
        run += vals[i];
    }
    if (t == SCAN_T - 1) btot[b] = sd[t];
}

__global__ __launch_bounds__(SCAN_T) void scan2_kernel(int* __restrict__ btot, int nb)
{
    __shared__ int sd[SCAN_T];
    int t = threadIdx.x;
    int orig = (t < nb) ? btot[t] : 0;
    sd[t] = orig;
    __syncthreads();
    for (int off = 1; off < SCAN_T; off <<= 1) {
        int x = (t >= off) ? sd[t - off] : 0;
        __syncthreads();
        sd[t] += x;
        __syncthreads();
    }
    if (t < nb) btot[t] = sd[t] - orig;
}

__global__ __launch_bounds__(SCAN_T) void scan3_kernel(
    int* __restrict__ roff, int* __restrict__ cur, const int* __restrict__ btot, int n)
{
    int add = btot[blockIdx.x];
    int base = blockIdx.x * SCAN_E + threadIdx.x;
    #pragma unroll
    for (int i = 0; i < 8; ++i) {
        int idx = base + i * SCAN_T;
        if (idx < n) { int val = roff[idx] + add; roff[idx] = val; cur[idx] = val; }
    }
}

// ---------------------------------------------------------------------------
// Scatter with 8 edges/thread ILP: 8 independent atomicAdds in flight.
// ---------------------------------------------------------------------------
__global__ __launch_bounds__(256) void scatter_kernel(
    const int* __restrict__ row, const int* __restrict__ col,
    int* __restrict__ cur, int* __restrict__ ecol, int E)
{
    int t = blockIdx.x * TPB + threadIdx.x;
    int base = t * EDGE_B;
    if (base >= E) return;
    if (base + EDGE_B <= E) {
        int4 r0 = *(const int4*)(row + base);
        int4 r1 = *(const int4*)(row + base + 4);
        int4 c0 = *(const int4*)(col + base);
        int4 c1 = *(const int4*)(col + base + 4);
        int rr[8] = {r0.x, r0.y, r0.z, r0.w, r1.x, r1.y, r1.z, r1.w};
        int cc[8] = {c0.x, c0.y, c0.z, c0.w, c1.x, c1.y, c1.z, c1.w};
        int pos[8];
        #pragma unroll
        for (int i = 0; i < 8; ++i) pos[i] = atomicAdd(&cur[rr[i]], 1);
        #pragma unroll
        for (int i = 0; i < 8; ++i) ecol[pos[i]] = cc[i];
    } else {
        for (int i = base; i < E; ++i) {
            int pos = atomicAdd(&cur[row[i]], 1);
            ecol[pos] = col[i];
        }
    }
}

// ---------------------------------------------------------------------------
// Fused attention, bf16, interleaved kv. One wave per dest node, lane = j*8+h.
// Per (edge, head): one contiguous 64B read (k:32B | v:32B).
// ao aliases q (wave reads q[i] into regs before storing ao[i]).
// ---------------------------------------------------------------------------
__global__ __launch_bounds__(256) void attn_kernel(
    const unsigned short* q, const unsigned short* __restrict__ kv,
    const int* __restrict__ roff, const int* __restrict__ cnt,
    const int* __restrict__ ecol, unsigned short* ao, int n)
{
    int wave = threadIdx.x >> 6;
    int lane = threadIdx.x & 63;
    int i = blockIdx.x * 4 + wave;
    if (i >= n) return;
    int hh = lane & 7;
    int j  = lane >> 3;

    float qf[16];
    {
        const uint4* qp = (const uint4*)(q + (size_t)i * 128 + hh * 16);
        uint4 a = qp[0], b = qp[1];
        qf[0] = bf2f_lo(a.x);  qf[1] = bf2f_hi(a.x);  qf[2]  = bf2f_lo(a.y);  qf[3]  = bf2f_hi(a.y);
        qf[4] = bf2f_lo(a.z);  qf[5] = bf2f_hi(a.z);  qf[6]  = bf2f_lo(a.w);  qf[7]  = bf2f_hi(a.w);
        qf[8] = bf2f_lo(b.x);  qf[9] = bf2f_hi(b.x);  qf[10] = bf2f_lo(b.y);  qf[11] = bf2f_hi(b.y);
        qf[12]= bf2f_lo(b.z);  qf[13]= bf2f_hi(b.z);  qf[14] = bf2f_lo(b.w);  qf[15] = bf2f_hi(b.w);
    }

    float s = 0.f;
    float acc[16];
    #pragma unroll
    for (int d = 0; d < 16; ++d) acc[d] = 0.f;

    int start = roff[i];
    int end   = start + cnt[i];
    for (int p = start + j; p < end; p += 8) {
        int c = ecol[p];
        const uint4* kp = (const uint4*)(kv + (size_t)c * 256 + hh * 32);
        uint4 ka = kp[0], kb = kp[1];   // k fragment (32B)
        uint4 va = kp[2], vb = kp[3];   // v fragment (32B), same 64B line
        float dot;
        dot = qf[0] * bf2f_lo(ka.x);
        dot = fmaf(qf[1],  bf2f_hi(ka.x), dot); dot = fmaf(qf[2],  bf2f_lo(ka.y), dot);
        dot = fmaf(qf[3],  bf2f_hi(ka.y), dot); dot = fmaf(qf[4],  bf2f_lo(ka.z), dot);
        dot = fmaf(qf[5],  bf2f_hi(ka.z), dot); dot = fmaf(qf[6],  bf2f_lo(ka.w), dot);
        dot = fmaf(qf[7],  bf2f_hi(ka.w), dot); dot = fmaf(qf[8],  bf2f_lo(kb.x), dot);
        dot = fmaf(qf[9],  bf2f_hi(kb.x), dot); dot = fmaf(qf[10], bf2f_lo(kb.y), dot);
        dot = fmaf(qf[11], bf2f_hi(kb.y), dot); dot = fmaf(qf[12], bf2f_lo(kb.z), dot);
        dot = fmaf(qf[13], bf2f_hi(kb.z), dot); dot = fmaf(qf[14], bf2f_lo(kb.w), dot);
        dot = fmaf(qf[15], bf2f_hi(kb.w), dot);
        float ev = __expf(dot);
        s += ev;
        acc[0]  = fmaf(ev, bf2f_lo(va.x), acc[0]);  acc[1]  = fmaf(ev, bf2f_hi(va.x), acc[1]);
        acc[2]  = fmaf(ev, bf2f_lo(va.y), acc[2]);  acc[3]  = fmaf(ev, bf2f_hi(va.y), acc[3]);
        acc[4]  = fmaf(ev, bf2f_lo(va.z), acc[4]);  acc[5]  = fmaf(ev, bf2f_hi(va.z), acc[5]);
        acc[6]  = fmaf(ev, bf2f_lo(va.w), acc[6]);  acc[7]  = fmaf(ev, bf2f_hi(va.w), acc[7]);
        acc[8]  = fmaf(ev, bf2f_lo(vb.x), acc[8]);  acc[9]  = fmaf(ev, bf2f_hi(vb.x), acc[9]);
        acc[10] = fmaf(ev, bf2f_lo(vb.y), acc[10]); acc[11] = fmaf(ev, bf2f_hi(vb.y), acc[11]);
        acc[12] = fmaf(ev, bf2f_lo(vb.z), acc[12]); acc[13] = fmaf(ev, bf2f_hi(vb.z), acc[13]);
        acc[14] = fmaf(ev, bf2f_lo(vb.w), acc[14]); acc[15] = fmaf(ev, bf2f_hi(vb.w), acc[15]);
    }

    #pragma unroll
    for (int m = 8; m <= 32; m <<= 1) {
        s += __shfl_xor(s, m);
        #pragma unroll
        for (int d = 0; d < 16; ++d) acc[d] += __shfl_xor(acc[d], m);
    }

    if (j == 0) {
        float inv = (s > 0.f) ? 1.f / s : 0.f;
        unsigned int w[8];
        #pragma unroll
        for (int d = 0; d < 8; ++d)
            w[d] = (unsigned int)f2bf(acc[2 * d] * inv) |
                   ((unsigned int)f2bf(acc[2 * d + 1] * inv) << 16);
        uint4* op = (uint4*)(ao + (size_t)i * 128 + hh * 16);
        op[0] = make_uint4(w[0], w[1], w[2], w[3]);
        op[1] = make_uint4(w[4], w[5], w[6], w[7]);
    }
}

// ---------------------------------------------------------------------------
// Output projection via bf16 MFMA: out = ao @ Wo^T + bo (fp32 out).
// ---------------------------------------------------------------------------
__global__ __launch_bounds__(256) void outproj_kernel(
    const unsigned short* __restrict__ ao, const float* __restrict__ Wo,
    const float* __restrict__ bo, float* __restrict__ out, int n)
{
    __shared__ unsigned short wl[128][32];
    __shared__ float bias_lds[128];

    const int tid  = threadIdx.x;
    const int nb   = blockIdx.x * 64;
    const int wv   = tid >> 6;
    const int lane = tid & 63;
    const int jj   = lane & 15;
    const int g    = lane >> 4;

    if (tid < 128) bias_lds[tid] = bo[tid];

    const int node_a = nb + wv * 16 + jj;
    bf16x8 afrag[4];
    #pragma unroll
    for (int kk = 0; kk < 4; ++kk) {
        if (node_a < n)
            afrag[kk] = *(const bf16x8*)(ao + (size_t)node_a * 128 + kk * 32 + g * 8);
        else {
            bf16x8 z;
            #pragma unroll
            for (int i = 0; i < 8; ++i) z[i] = 0;
            afrag[kk] = z;
        }
    }

    f32x4 acc[8];
    #pragma unroll
    for (int ct = 0; ct < 8; ++ct) { f32x4 z = {0.f, 0.f, 0.f, 0.f}; acc[ct] = z; }

    for (int kk = 0; kk < 4; ++kk) {
        __syncthreads();
        #pragma unroll
        for (int it = 0; it < 16; ++it) {
            int idx = tid + it * TPB;   // 0..4095
            int jr = idx >> 5, c = idx & 31;
            wl[jr][c] = f2bf(Wo[(size_t)jr * 128 + origcol(kk * 32 + c)]);
        }
        __syncthreads();
        #pragma unroll
        for (int ct = 0; ct < 8; ++ct) {
            bf16x8 b = *(const bf16x8*)(&wl[ct * 16 + jj][g * 8]);
            acc[ct] = __builtin_amdgcn_mfma_f32_16x16x32_bf16(afrag[kk], b, acc[ct], 0, 0, 0);
        }
    }

    #pragma unroll
    for (int ct = 0; ct < 8; ++ct) {
        int jr = ct * 16 + jj;
        float bsv = bias_lds[jr];
        #pragma unroll
        for (int r = 0; r < 4; ++r) {
            int node = nb + wv * 16 + g * 4 + r;
            if (node < n)
                out[(size_t)node * 128 + jr] = acc[ct][r] + bsv;
        }
    }
}

// ---------------------------------------------------------------------------

extern "C" void kernel_launch(void* const* d_in, const int* in_sizes, int n_in,
                              void* d_out, int out_size, void* d_ws, size_t ws_size,
                              hipStream_t stream)
{
    const float* h   = (const float*)d_in[0];
    const int*   row = (const int*)d_in[1];
    const int*   col = (const int*)d_in[2];
    const float* Wq  = (const float*)d_in[3];
    const float* bq  = (const float*)d_in[4];
    const float* Wk  = (const float*)d_in[5];
    const float* bk  = (const float*)d_in[6];
    const float* Wv  = (const float*)d_in[7];
    const float* bv  = (const float*)d_in[8];
    const float* Wo  = (const float*)d_in[9];
    const float* bo  = (const float*)d_in[10];

    const int n = in_sizes[0] / 128;
    const int E = in_sizes[1];
    float* out = (float*)d_out;

    // workspace layout
    char* ws = (char*)d_ws;
    unsigned short* q  = (unsigned short*)ws; ws += (size_t)n * 128 * sizeof(unsigned short);
    unsigned short* kv = (unsigned short*)ws; ws += (size_t)n * 256 * sizeof(unsigned short);
    int* cnt  = (int*)ws; ws += (size_t)n * sizeof(int);
    int* roff = (int*)ws; ws += (size_t)n * sizeof(int);
    int* cur  = (int*)ws; ws += (size_t)n * sizeof(int);
    int* ecol = (int*)ws; ws += (size_t)E * sizeof(int);
    int* btot = (int*)ws; ws += 256 * sizeof(int);
    unsigned short* ao = q;   // alias: attn reads q[i] into regs before storing ao[i]
    if (ws_size < (size_t)(ws - (char*)d_ws)) return;

    hipMemsetAsync(cnt, 0, (size_t)n * sizeof(int), stream);

    const int projBlocks = (n + 63) / 64;
    const int histBlocks = (E + TPB * EDGE_B - 1) / (TPB * EDGE_B);
    proj_hist_kernel<<<projBlocks + histBlocks, TPB, 0, stream>>>(
        h, Wq, bq, Wk, bk, Wv, bv, q, kv, n, row, cnt, E, projBlocks);

    int nsb = (n + SCAN_E - 1) / SCAN_E;   // 49 for n=100k (<= 256)
    scan1_kernel<<<nsb, SCAN_T, 0, stream>>>(cnt, roff, btot, n);
    scan2_kernel<<<1, SCAN_T, 0, stream>>>(btot, nsb);
    scan3_kernel<<<nsb, SCAN_T, 0, stream>>>(roff, cur, btot, n);

    int scBlocks = (E + TPB * EDGE_B - 1) / (TPB * EDGE_B);
    scatter_kernel<<<scBlocks, TPB, 0, stream>>>(row, col, cur, ecol, E);

    attn_kernel<<<(n + 3) / 4, TPB, 0, stream>>>(q, kv, roff, cnt, ecol, ao, n);

    outproj_kernel<<<(n + 63) / 64, TPB, 0, stream>>>(ao, Wo, bo, out, n);
}